// Round 5
// baseline (550.222 us; speedup 1.0000x reference)
//
#include <hip/hip_runtime.h>
#include <hip/hip_bf16.h>
#include <math.h>

// Shapes: B=1, S=512, N=384, c_m=64, c_z=128, H=8, c=32  (HC = 256)
//
// Pipeline:
//  k0_prep: W4 -> W4p[64][256] bf16 with pi-PERMUTED k axis (see below);
//           W1|W3 -> W13s[512][64] bf16 chunk-swizzled for k1's DMA.
//  k1     : m = LN(m_si) -> bf16 LDS; MFMA GEMM vs W13 (K=64):
//           v = m@W1 stored TRANSPOSED v_tg[s][hc][j];
//           g = sigmoid(m@W3) -> g_p[s][j][k] with pi-permuted k columns.
//  k2     : b = LN(z)@W2 -> w_buf[h][i][j] fp32
//  k3a/m/b: softmax over i -> w_bf[h][i][j] bf16
//  k4     : einsum via OPERAND-SWAPPED MFMA: D[c][i] puts i at lane&15 ==
//           exactly the A-frag row layout of the W4 GEMM -> the epilogue
//           consumes the gated accumulators IN-REGISTER (no o_l LDS
//           transpose, no in-loop gate loads). pi maps the MFMA's natural
//           per-lane (quad,e)->c ordering onto the hc axis so W4/g line up.
//
// pi(32h + quad*8 + e) = 32h + (e<4 ? quad*4+e : 16 + quad*4 + (e-4))

typedef __attribute__((ext_vector_type(8))) short bf16x8;   // 8 bf16 = 4 VGPRs
typedef __attribute__((ext_vector_type(4))) float f32x4;
typedef unsigned int u32;

__device__ inline float b2f(short v) {
    union { float f; u32 u; } t; t.u = ((u32)(unsigned short)v) << 16; return t.f;
}

__global__ __launch_bounds__(256) void k0_prep(
    const float* __restrict__ W4, const float* __restrict__ W1,
    const float* __restrict__ W3,
    __hip_bfloat16* __restrict__ W4p,    // [64 d][256 k]  k = pi-permuted hc
    __hip_bfloat16* __restrict__ W13s)   // [512][64] chunk-swizzled
{
    int idx = blockIdx.x * 256 + threadIdx.x;   // 192*256 = 49152
    if (idx < 16384) {
        int d = idx >> 8, k = idx & 255;
        int koff = k & 31, h = k >> 5;
        int quad = koff >> 3, e = koff & 7;
        int c = (e < 4) ? (quad * 4 + e) : (16 + quad * 4 + (e - 4));
        int hc = h * 32 + c;
        W4p[idx] = __float2bfloat16(W4[hc * 64 + d]);
    } else {
        int t = idx - 16384;            // 0..32767
        int n = t >> 6, k = t & 63;
        float v = (n < 256) ? W1[k * 256 + n] : W3[k * 256 + (n - 256)];
        int dst = n * 64 + ((((k >> 3) ^ (n & 7))) << 3) + (k & 7);
        W13s[dst] = __float2bfloat16(v);
    }
}

// ---------------------------------------------------------------------------
// k1: LN + dual GEMM via MFMA. grid = 512*3 = 1536 blocks, 256 threads.
__global__ __launch_bounds__(256) void k1_ln_mv(
    const float* __restrict__ m_si,
    const float* __restrict__ gamma_m, const float* __restrict__ beta_m,
    const __hip_bfloat16* __restrict__ W13s, // [512][64] bf16 pre-swizzled
    __hip_bfloat16* __restrict__ v_tg,   // [512][256 hc][384 j]
    __hip_bfloat16* __restrict__ g_p)    // [512][384 j][256 k(pi)]
{
    __shared__ short a_t[128 * 64];     // 16384 B: m̂, chunk-swizzled
    __shared__ short b_t[512 * 64];     // 65536 B: W13, chunk-swizzled
    const int bx = blockIdx.x;
    const int s = bx / 3, j0 = (bx % 3) * 128;
    const int tid = threadIdx.x;
    const int lane = tid & 63, wv = tid >> 6;
    const int col = lane & 15, quad = lane >> 4;

    // ---- stage W13 into LDS (async DMA; overlaps the LN VALU phase) ----
    {
        const short* src = (const short*)W13s;
        #pragma unroll
        for (int i = 0; i < 16; i++) {
            __builtin_amdgcn_global_load_lds(
                (const __attribute__((address_space(1))) u32*)
                    (src + i * 2048 + wv * 512 + lane * 8),
                (__attribute__((address_space(3))) u32*)(b_t + i * 2048 + wv * 512),
                16, 0, 0);
        }
    }

    // ---- LN: 32 rows per wave, lane = channel; write bf16 m̂ swizzled ----
    {
        const float gm = gamma_m[lane], bm = beta_m[lane];
        const float* mrow = m_si + (size_t)(s * 384 + j0) * 64;
        const int cl = lane >> 3, e = lane & 7;
        #pragma unroll 4
        for (int rr = 0; rr < 32; rr++) {
            int r = wv * 32 + rr;
            float x = mrow[r * 64 + lane];
            float s1 = x, s2 = x * x;
            #pragma unroll
            for (int off = 32; off > 0; off >>= 1) {
                s1 += __shfl_xor(s1, off, 64);
                s2 += __shfl_xor(s2, off, 64);
            }
            float mu  = s1 * (1.0f / 64.0f);
            float var = s2 * (1.0f / 64.0f) - mu * mu;
            float rs  = rsqrtf(var + 1e-5f);
            __hip_bfloat16 mh = __float2bfloat16((x - mu) * rs * gm + bm);
            a_t[r * 64 + ((cl ^ (r & 7)) << 3) + e] = *(short*)&mh;
        }
    }
    __syncthreads();    // drains DMA (vmcnt 0) + LDS writes

    // ---- GEMM: block tile 128 x 512, wave tile 64 x 64 per n-step ----
    const int wm = wv >> 1, wn = wv & 1;

    bf16x8 mf[4][2];    // m̂ A/B-frags, fixed across all n-steps
    #pragma unroll
    for (int mt = 0; mt < 4; mt++) {
        int r = wm * 64 + mt * 16 + col;
        #pragma unroll
        for (int ks = 0; ks < 2; ks++) {
            int c = ks * 4 + quad;
            mf[mt][ks] = *(const bf16x8*)&a_t[r * 64 + ((c ^ (r & 7)) << 3)];
        }
    }

    short* vbase = (short*)v_tg + (size_t)s * 98304;          // [hc][384]
    __hip_bfloat16* gb = g_p + (size_t)s * 98304;             // [384][256]

    #pragma unroll 1
    for (int step = 0; step < 4; step++) {
        bf16x8 wf[4][2];
        #pragma unroll
        for (int nt = 0; nt < 4; nt++) {
            int n = step * 128 + wn * 64 + nt * 16 + col;
            #pragma unroll
            for (int ks = 0; ks < 2; ks++) {
                int c = ks * 4 + quad;
                wf[nt][ks] = *(const bf16x8*)&b_t[n * 64 + ((c ^ (n & 7)) << 3)];
            }
        }

        if (step < 2) {
            // v half: operand-swapped -> D[n][j], matches v_tg transpose
            f32x4 acc[4][4];
            #pragma unroll
            for (int nt = 0; nt < 4; nt++)
                #pragma unroll
                for (int mt = 0; mt < 4; mt++)
                    acc[nt][mt] = (f32x4){0.f, 0.f, 0.f, 0.f};
            #pragma unroll
            for (int ks = 0; ks < 2; ks++)
                #pragma unroll
                for (int nt = 0; nt < 4; nt++)
                    #pragma unroll
                    for (int mt = 0; mt < 4; mt++)
                        acc[nt][mt] = __builtin_amdgcn_mfma_f32_16x16x32_bf16(
                            wf[nt][ks], mf[mt][ks], acc[nt][mt], 0, 0, 0);
            #pragma unroll
            for (int nt = 0; nt < 4; nt++)
                #pragma unroll
                for (int mt = 0; mt < 4; mt++) {
                    int jg = j0 + wm * 64 + mt * 16 + col;
                    #pragma unroll
                    for (int reg = 0; reg < 4; reg++) {
                        int n = step * 128 + wn * 64 + nt * 16 + quad * 4 + reg;
                        __hip_bfloat16 t = __float2bfloat16(acc[nt][mt][reg]);
                        vbase[n * 384 + jg] = *(short*)&t;
                    }
                }
        } else {
            // g half: normal orientation -> D[j][hc]; store with pi^-1 column
            f32x4 acc[4][4];
            #pragma unroll
            for (int mt = 0; mt < 4; mt++)
                #pragma unroll
                for (int nt = 0; nt < 4; nt++)
                    acc[mt][nt] = (f32x4){0.f, 0.f, 0.f, 0.f};
            #pragma unroll
            for (int ks = 0; ks < 2; ks++)
                #pragma unroll
                for (int mt = 0; mt < 4; mt++)
                    #pragma unroll
                    for (int nt = 0; nt < 4; nt++)
                        acc[mt][nt] = __builtin_amdgcn_mfma_f32_16x16x32_bf16(
                            mf[mt][ks], wf[nt][ks], acc[mt][nt], 0, 0, 0);
            #pragma unroll
            for (int mt = 0; mt < 4; mt++)
                #pragma unroll
                for (int nt = 0; nt < 4; nt++) {
                    int n = (step - 2) * 128 + wn * 64 + nt * 16 + col;
                    int c32 = n & 31;
                    int koff = ((c32 & 15) >> 2) * 8 + (c32 & 3)
                             + ((c32 & 16) ? 4 : 0);
                    int kn = (n & ~31) | koff;
                    #pragma unroll
                    for (int reg = 0; reg < 4; reg++) {
                        int jg = j0 + wm * 64 + mt * 16 + quad * 4 + reg;
                        float gv = 1.0f / (1.0f + __expf(-acc[mt][nt][reg]));
                        gb[(size_t)jg * 256 + kn] = __float2bfloat16(gv);
                    }
                }
        }
    }
}

// ---------------------------------------------------------------------------
// k2: 64 rows/block, 4 waves, one wave per row step. grid = 2304.
__global__ __launch_bounds__(256) void k2_ln_z(
    const float* __restrict__ z,
    const float* __restrict__ gamma_z, const float* __restrict__ beta_z,
    const float* __restrict__ W2, float* __restrict__ b_buf)
{
    const int tid = threadIdx.x;
    const int lane = tid & 63, wv = tid >> 6;
    const int R0 = blockIdx.x * 64;
    __shared__ float part[64][9];       // [row_local][h], stride 9 = conflict-free

    float2 g2 = *(const float2*)&gamma_z[lane * 2];
    float2 be2 = *(const float2*)&beta_z[lane * 2];
    float4 w2a = *(const float4*)&W2[lane * 16];
    float4 w2b = *(const float4*)&W2[lane * 16 + 4];
    float4 w2c = *(const float4*)&W2[lane * 16 + 8];
    float4 w2d = *(const float4*)&W2[lane * 16 + 12];

    const bool hi4 = (lane & 4) != 0;
    const bool hi2 = (lane & 2) != 0;
    const bool hi1 = (lane & 1) != 0;

    float2 zx = *(const float2*)&z[(size_t)(R0 + wv * 16) * 128 + lane * 2];
    #pragma unroll 1
    for (int rr = 0; rr < 16; rr++) {
        const int rl = wv * 16 + rr;
        float x0 = zx.x, x1 = zx.y;
        if (rr < 15)
            zx = *(const float2*)&z[(size_t)(R0 + rl + 1) * 128 + lane * 2];

        float s1 = x0 + x1, s2 = x0 * x0 + x1 * x1;
        #pragma unroll
        for (int off = 32; off > 0; off >>= 1) {
            s1 += __shfl_xor(s1, off, 64);
            s2 += __shfl_xor(s2, off, 64);
        }
        float mu  = s1 * (1.0f / 128.0f);
        float var = s2 * (1.0f / 128.0f) - mu * mu;
        float rs  = rsqrtf(var + 1e-5f);
        float mh0 = (x0 - mu) * rs * g2.x + be2.x;
        float mh1 = (x1 - mu) * rs * g2.y + be2.y;

        float p[8];
        p[0] = fmaf(mh0, w2a.x, mh1 * w2c.x);
        p[1] = fmaf(mh0, w2a.y, mh1 * w2c.y);
        p[2] = fmaf(mh0, w2a.z, mh1 * w2c.z);
        p[3] = fmaf(mh0, w2a.w, mh1 * w2c.w);
        p[4] = fmaf(mh0, w2b.x, mh1 * w2d.x);
        p[5] = fmaf(mh0, w2b.y, mh1 * w2d.y);
        p[6] = fmaf(mh0, w2b.z, mh1 * w2d.z);
        p[7] = fmaf(mh0, w2b.w, mh1 * w2d.w);

        float t[4];
        #pragma unroll
        for (int k = 0; k < 4; k++) {
            float keep = hi4 ? p[k + 4] : p[k];
            float send = hi4 ? p[k] : p[k + 4];
            t[k] = keep + __shfl_xor(send, 4, 64);
        }
        float u[2];
        #pragma unroll
        for (int k = 0; k < 2; k++) {
            float keep = hi2 ? t[k + 2] : t[k];
            float send = hi2 ? t[k] : t[k + 2];
            u[k] = keep + __shfl_xor(send, 2, 64);
        }
        float vsum;
        {
            float keep = hi1 ? u[1] : u[0];
            float send = hi1 ? u[0] : u[1];
            vsum = keep + __shfl_xor(send, 1, 64);
        }
        vsum += __shfl_xor(vsum, 8, 64);
        vsum += __shfl_xor(vsum, 16, 64);
        vsum += __shfl_xor(vsum, 32, 64);
        if (lane < 8) part[rl][lane] = vsum;   // h = lane
    }
    __syncthreads();

    {
        int h0 = tid >> 6, rl = tid & 63;
        b_buf[(size_t)h0 * 147456 + R0 + rl]       = part[rl][h0];
        b_buf[(size_t)(h0 + 4) * 147456 + R0 + rl] = part[rl][h0 + 4];
    }
}

// ---------------------------------------------------------------------------
// k3a: partial online softmax over 16-i chunks. grid = 8*24 = 192, block 128.
__global__ __launch_bounds__(128) void k3a_part(
    const float* __restrict__ w_buf, float* __restrict__ pm, float* __restrict__ pl)
{
    const int h = blockIdx.x / 24, ic = blockIdx.x % 24;
    const int i0 = ic * 16;
    const int tid = threadIdx.x;
    const float* base = w_buf + ((size_t)h * 384 + i0) * 384;

    float m0 = -INFINITY, m1 = -INFINITY, m2 = -INFINITY;
    float l0 = 0.f, l1 = 0.f, l2 = 0.f;
    #pragma unroll 4
    for (int ii = 0; ii < 16; ii++) {
        float x0 = base[ii * 384 + tid];
        float x1 = base[ii * 384 + tid + 128];
        float x2 = base[ii * 384 + tid + 256];
        float n0 = fmaxf(m0, x0);
        l0 = l0 * __expf(m0 - n0) + __expf(x0 - n0); m0 = n0;
        float n1 = fmaxf(m1, x1);
        l1 = l1 * __expf(m1 - n1) + __expf(x1 - n1); m1 = n1;
        float n2 = fmaxf(m2, x2);
        l2 = l2 * __expf(m2 - n2) + __expf(x2 - n2); m2 = n2;
    }
    float* pmb = pm + ((size_t)h * 24 + ic) * 384;
    float* plb = pl + ((size_t)h * 24 + ic) * 384;
    pmb[tid]       = m0;  plb[tid]       = l0;
    pmb[tid + 128] = m1;  plb[tid + 128] = l1;
    pmb[tid + 256] = m2;  plb[tid + 256] = l2;
}

// k3m: combine 24 partials -> M, invL. grid = 8 blocks, 384 threads.
__global__ __launch_bounds__(384) void k3m_comb(
    const float* __restrict__ pm, const float* __restrict__ pl,
    float* __restrict__ Mf, float* __restrict__ invLf)
{
    const int h = blockIdx.x, j = threadIdx.x;
    float M = -INFINITY, L = 0.f;
    #pragma unroll 4
    for (int ic = 0; ic < 24; ic++) {
        float m = pm[((size_t)h * 24 + ic) * 384 + j];
        float l = pl[((size_t)h * 24 + ic) * 384 + j];
        float nM = fmaxf(M, m);
        L = L * __expf(M - nM) + l * __expf(m - nM);
        M = nM;
    }
    Mf[h * 384 + j] = M;
    invLf[h * 384 + j] = 1.0f / L;
}

// k3b: write normalized bf16 weights. grid = 192, block 128.
__global__ __launch_bounds__(128) void k3b_write(
    const float* __restrict__ w_buf, const float* __restrict__ Mf,
    const float* __restrict__ invLf, __hip_bfloat16* __restrict__ w_bf)
{
    const int h = blockIdx.x / 24, ic = blockIdx.x % 24;
    const int i0 = ic * 16;
    const int tid = threadIdx.x;
    const float* base = w_buf + ((size_t)h * 384 + i0) * 384;
    __hip_bfloat16* ob = w_bf + ((size_t)h * 384 + i0) * 384;

    float M0 = Mf[h * 384 + tid],       iL0 = invLf[h * 384 + tid];
    float M1 = Mf[h * 384 + tid + 128], iL1 = invLf[h * 384 + tid + 128];
    float M2 = Mf[h * 384 + tid + 256], iL2 = invLf[h * 384 + tid + 256];
    #pragma unroll 4
    for (int ii = 0; ii < 16; ii++) {
        float x0 = base[ii * 384 + tid];
        float x1 = base[ii * 384 + tid + 128];
        float x2 = base[ii * 384 + tid + 256];
        ob[ii * 384 + tid]       = __float2bfloat16(__expf(x0 - M0) * iL0);
        ob[ii * 384 + tid + 128] = __float2bfloat16(__expf(x1 - M1) * iL1);
        ob[ii * 384 + tid + 256] = __float2bfloat16(__expf(x2 - M2) * iL2);
    }
}

// ---------------------------------------------------------------------------
// k4: MFMA einsum + gate + @W4.  grid = 512*6 = 3072 blocks, 256 threads.
//
// R5 restructure (post-mortem R0-R4: 250-265us INVARIANT across staging
// schemes => bottleneck was the shared structure, not staging):
//  - OPERAND-SWAPPED einsum: acc[h] = mfma(A=V-frag, B=W-frag) -> D[c][i]
//    with i = lane&15 == the A-frag row layout of the W4 GEMM. The gated
//    accumulators feed the W4 MFMAs IN-REGISTER; o_l LDS transpose DELETED
//    (was 3200 bank-conflict cy/block and an LDS round-trip per h).
//  - gate loads hoisted OUT of the loop (pi-layout g_p: one 16B load per h
//    per lane, 64B-coalesced per col-group; issued in prologue).
//  - 8 barrier intervals (not 16): per interval 24 MFMA + 24 ds_read_b128
//    + 12 W-loads (issued BEFORE the STAGE so their FIFO drain does not
//    force the prefetch to complete) + 1 STAGE (6 async DMA).
//  - LDS = 2 x 24576 = 49152 B  -> 3 blocks/CU (12 waves), launch_bounds
//    (256,3). Three independent blocks give cross-block latency hiding.
__global__ __launch_bounds__(256, 3) void k4_mfma(
    const __hip_bfloat16* __restrict__ w_bf,   // [8][384 i][384 j]
    const __hip_bfloat16* __restrict__ v_tg,   // [512][8][32 c][384 j]
    const __hip_bfloat16* __restrict__ g_p,    // [512][384 i][256 k(pi)]
    const __hip_bfloat16* __restrict__ W4p,    // [64 d][256 k(pi)]
    float* __restrict__ out)                   // [512][384][64]
{
    __shared__ short v_t[2][12288];            // 2 x 24576 B: [32 c][384 j]
    const int bx0 = blockIdx.x;
    const int bx = (bx0 & 7) * 384 + (bx0 >> 3);   // bijective XCD swizzle
    const int s = bx / 6, i0 = (bx % 6) * 64;
    const int tid = threadIdx.x;
    const int lane = tid & 63, wv = tid >> 6;
    const int col = lane & 15, quad = lane >> 4;
    const int swz = col & 7;

    // stage geometry: 1536 16B-chunks; chunk p = r*256 + tid; row = p/48;
    // source chunk = (p%48) ^ (row&7)  (inverse swizzle on global source)
    int srow[6], skc[6];
    #pragma unroll
    for (int r = 0; r < 6; r++) {
        int p = r * 256 + tid;
        int row = p / 48;
        srow[r] = row;
        skc[r] = (p - row * 48) ^ (row & 7);
    }

    const short* vslab = (const short*)v_tg + (size_t)s * 98304;
    const short* wbase = (const short*)w_bf
        + (size_t)(i0 + wv * 16 + col) * 384 + quad * 8;

    auto STAGE = [&](int buf, int hh) {
        const short* src = vslab + hh * 12288;
        #pragma unroll
        for (int r = 0; r < 6; r++) {
            __builtin_amdgcn_global_load_lds(
                (const __attribute__((address_space(1))) u32*)
                    (src + srow[r] * 384 + skc[r] * 8),
                (__attribute__((address_space(3))) u32*)
                    (&v_t[buf][r * 2048 + wv * 512]),
                16, 0, 0);
        }
    };

    // prologue: gates (independent of the loop; cold-HBM latency hides
    // under the whole h-loop) + first V stage
    const short* gbase = (const short*)g_p
        + (size_t)(s * 384 + i0 + wv * 16 + col) * 256 + quad * 8;
    bf16x8 gf[8];
    #pragma unroll
    for (int h = 0; h < 8; h++)
        gf[h] = *(const bf16x8*)(gbase + h * 32);

    STAGE(0, 0);

    f32x4 acc[8][2];
    #pragma unroll
    for (int h = 0; h < 8; h++) {
        acc[h][0] = (f32x4){0.f, 0.f, 0.f, 0.f};
        acc[h][1] = (f32x4){0.f, 0.f, 0.f, 0.f};
    }

    #pragma unroll
    for (int h = 0; h < 8; h++) {
        __builtin_amdgcn_sched_barrier(0);
        asm volatile("s_waitcnt vmcnt(0)" ::: "memory");   // own S(h) done
        __builtin_amdgcn_s_barrier();                      // everyone's S(h)
        __builtin_amdgcn_sched_barrier(0);

        // W fragments for this h: issue BEFORE the stage so the compiler's
        // waits for them leave the S(h+1) prefetch in flight.
        bf16x8 wf[12];
        const short* wA = wbase + (size_t)h * 147456;
        #pragma unroll
        for (int ks = 0; ks < 12; ks++)
            wf[ks] = *(const bf16x8*)(wA + ks * 32);

        if (h < 7) STAGE((h + 1) & 1, h + 1);

        __builtin_amdgcn_s_setprio(1);
        #pragma unroll
        for (int ks = 0; ks < 12; ks++) {
            int ch = (ks * 4 + quad) ^ swz;
            bf16x8 a0 = *(const bf16x8*)&v_t[h & 1][col * 384 + ch * 8];
            bf16x8 a1 = *(const bf16x8*)&v_t[h & 1][(16 + col) * 384 + ch * 8];
            acc[h][0] = __builtin_amdgcn_mfma_f32_16x16x32_bf16(
                            a0, wf[ks], acc[h][0], 0, 0, 0);
            acc[h][1] = __builtin_amdgcn_mfma_f32_16x16x32_bf16(
                            a1, wf[ks], acc[h][1], 0, 0, 0);
        }
        __builtin_amdgcn_s_setprio(0);
    }

    // epilogue: gate in-register, pack to bf16 A-frags, W4 GEMM, store.
    // acc[h][half][reg] holds o(i = col, c = half*16 + quad*4 + reg, h);
    // paf[h] element e  = gated o at c(quad,e)  == A[row=col][k=32h+quad*8+e].
    bf16x8 paf[8];
    #pragma unroll
    for (int h = 0; h < 8; h++) {
        #pragma unroll
        for (int e = 0; e < 4; e++) {
            float v0 = acc[h][0][e] * b2f(gf[h][e]);
            float v1 = acc[h][1][e] * b2f(gf[h][4 + e]);
            __hip_bfloat16 t0 = __float2bfloat16(v0);
            __hip_bfloat16 t1 = __float2bfloat16(v1);
            paf[h][e]     = *(short*)&t0;
            paf[h][4 + e] = *(short*)&t1;
        }
    }

    f32x4 acc2[4];
    #pragma unroll
    for (int n = 0; n < 4; n++) acc2[n] = (f32x4){0.f, 0.f, 0.f, 0.f};
    #pragma unroll
    for (int h = 0; h < 8; h++) {
        #pragma unroll
        for (int n = 0; n < 4; n++) {
            bf16x8 b = *(const bf16x8*)((const short*)W4p
                        + (n * 16 + col) * 256 + h * 32 + quad * 8);
            acc2[n] = __builtin_amdgcn_mfma_f32_16x16x32_bf16(
                          paf[h], b, acc2[n], 0, 0, 0);
        }
    }
    float* obase = out + (size_t)(s * 384 + i0 + wv * 16 + quad * 4) * 64;
    #pragma unroll
    for (int n = 0; n < 4; n++)
        #pragma unroll
        for (int reg = 0; reg < 4; reg++)
            obase[reg * 64 + n * 16 + col] = acc2[n][reg];
}

// ---------------------------------------------------------------------------
extern "C" void kernel_launch(void* const* d_in, const int* in_sizes, int n_in,
                              void* d_out, int out_size, void* d_ws, size_t ws_size,
                              hipStream_t stream)
{
    const float* m_si    = (const float*)d_in[0];
    const float* z_ij    = (const float*)d_in[1];
    const float* gamma_m = (const float*)d_in[2];
    const float* beta_m  = (const float*)d_in[3];
    const float* W1      = (const float*)d_in[4];
    const float* gamma_z = (const float*)d_in[5];
    const float* beta_z  = (const float*)d_in[6];
    const float* W2      = (const float*)d_in[7];
    const float* W3      = (const float*)d_in[8];
    const float* W4      = (const float*)d_in[9];
    float* out = (float*)d_out;

    // ws layout (~209.0 MB):
    //   g_p  : 100663296 B   v_tg : 100663296 B   w_buf(fp32): 4718592 B
    //   w_bf : 2359296 B     W4p  : 32768 B
    //   pm/pl: 294912 B each   Mf/invLf: 12288 B each
    //   W13s : 65536 B, ALIASES w_buf (dead until k2; k1 reads before k2 writes)
    char* ws = (char*)d_ws;
    __hip_bfloat16* g_p  = (__hip_bfloat16*)ws;
    __hip_bfloat16* v_tg = (__hip_bfloat16*)(ws + 100663296);
    float*          w_buf = (float*)(ws + 201326592);
    __hip_bfloat16* W13s = (__hip_bfloat16*)(ws + 201326592);  // alias w_buf
    __hip_bfloat16* w_bf = (__hip_bfloat16*)(ws + 206045184);
    __hip_bfloat16* W4p  = (__hip_bfloat16*)(ws + 208404480);
    float* pm    = (float*)(ws + 208437248);
    float* pl    = (float*)(ws + 208732160);
    float* Mf    = (float*)(ws + 209027072);
    float* invLf = (float*)(ws + 209039360);

    k0_prep  <<<192,  256, 0, stream>>>(W4, W1, W3, W4p, W13s);
    k1_ln_mv <<<1536, 256, 0, stream>>>(m_si, gamma_m, beta_m, W13s, v_tg, g_p);
    k2_ln_z  <<<2304, 256, 0, stream>>>(z_ij, gamma_z, beta_z, W2, w_buf);
    k3a_part <<<192,  128, 0, stream>>>(w_buf, pm, pl);
    k3m_comb <<<8,    384, 0, stream>>>(pm, pl, Mf, invLf);
    k3b_write<<<192,  128, 0, stream>>>(w_buf, Mf, invLf, w_bf);
    k4_mfma  <<<3072, 256, 0, stream>>>(w_bf, v_tg, g_p, W4p, out);
}

// Round 6
// 516.334 us; speedup vs baseline: 1.0656x; 1.0656x over previous
//
#include <hip/hip_runtime.h>
#include <hip/hip_bf16.h>
#include <math.h>

// Shapes: B=1, S=512, N=384, c_m=64, c_z=128, H=8, c=32  (HC = 256)
//
// Pipeline:
//  k0_prep: W4 -> W4p[64][256] bf16 with pi-PERMUTED k axis (see below);
//           W1|W3 -> W13s[512][64] bf16 chunk-swizzled for k1's DMA.
//  k1     : m = LN(m_si) -> bf16 LDS; MFMA GEMM vs W13 (K=64):
//           v = m@W1 stored TRANSPOSED v_tg[s][hc][j];
//           g = sigmoid(m@W3) -> g_p[s][j][k] with pi-permuted k columns.
//  k2     : b = LN(z)@W2 -> w_buf[h][i][j] fp32
//  k3a/m/b: softmax over i -> w_bf[h][i][j] bf16
//  k4     : einsum via OPERAND-SWAPPED MFMA: D[c][i] puts i at lane&15 ==
//           exactly the A-frag row layout of the W4 GEMM -> the gated
//           accumulators feed the W4 MFMAs IN-REGISTER (no o_l transpose).
//           R6 fix vs R5: gate+pack PER-H inside the loop (4 VGPRs/h live,
//           not 8 f32/h) -> no scratch spills (R5: VGPR 84 + 380MB spill
//           traffic, WRITE_SIZE 49->267MB).
//
// pi(32h + quad*8 + e) = 32h + (e<4 ? quad*4+e : 16 + quad*4 + (e-4))

typedef __attribute__((ext_vector_type(8))) short bf16x8;   // 8 bf16 = 4 VGPRs
typedef __attribute__((ext_vector_type(4))) float f32x4;
typedef unsigned int u32;

__device__ inline float b2f(short v) {
    union { float f; u32 u; } t; t.u = ((u32)(unsigned short)v) << 16; return t.f;
}

__global__ __launch_bounds__(256) void k0_prep(
    const float* __restrict__ W4, const float* __restrict__ W1,
    const float* __restrict__ W3,
    __hip_bfloat16* __restrict__ W4p,    // [64 d][256 k]  k = pi-permuted hc
    __hip_bfloat16* __restrict__ W13s)   // [512][64] chunk-swizzled
{
    int idx = blockIdx.x * 256 + threadIdx.x;   // 192*256 = 49152
    if (idx < 16384) {
        int d = idx >> 8, k = idx & 255;
        int koff = k & 31, h = k >> 5;
        int quad = koff >> 3, e = koff & 7;
        int c = (e < 4) ? (quad * 4 + e) : (16 + quad * 4 + (e - 4));
        int hc = h * 32 + c;
        W4p[idx] = __float2bfloat16(W4[hc * 64 + d]);
    } else {
        int t = idx - 16384;            // 0..32767
        int n = t >> 6, k = t & 63;
        float v = (n < 256) ? W1[k * 256 + n] : W3[k * 256 + (n - 256)];
        int dst = n * 64 + ((((k >> 3) ^ (n & 7))) << 3) + (k & 7);
        W13s[dst] = __float2bfloat16(v);
    }
}

// ---------------------------------------------------------------------------
// k1: LN + dual GEMM via MFMA. grid = 512*3 = 1536 blocks, 256 threads.
__global__ __launch_bounds__(256) void k1_ln_mv(
    const float* __restrict__ m_si,
    const float* __restrict__ gamma_m, const float* __restrict__ beta_m,
    const __hip_bfloat16* __restrict__ W13s, // [512][64] bf16 pre-swizzled
    __hip_bfloat16* __restrict__ v_tg,   // [512][256 hc][384 j]
    __hip_bfloat16* __restrict__ g_p)    // [512][384 j][256 k(pi)]
{
    __shared__ short a_t[128 * 64];     // 16384 B: m̂, chunk-swizzled
    __shared__ short b_t[512 * 64];     // 65536 B: W13, chunk-swizzled
    const int bx = blockIdx.x;
    const int s = bx / 3, j0 = (bx % 3) * 128;
    const int tid = threadIdx.x;
    const int lane = tid & 63, wv = tid >> 6;
    const int col = lane & 15, quad = lane >> 4;

    // ---- stage W13 into LDS (async DMA; overlaps the LN VALU phase) ----
    {
        const short* src = (const short*)W13s;
        #pragma unroll
        for (int i = 0; i < 16; i++) {
            __builtin_amdgcn_global_load_lds(
                (const __attribute__((address_space(1))) u32*)
                    (src + i * 2048 + wv * 512 + lane * 8),
                (__attribute__((address_space(3))) u32*)(b_t + i * 2048 + wv * 512),
                16, 0, 0);
        }
    }

    // ---- LN: 32 rows per wave, lane = channel; write bf16 m̂ swizzled ----
    {
        const float gm = gamma_m[lane], bm = beta_m[lane];
        const float* mrow = m_si + (size_t)(s * 384 + j0) * 64;
        const int cl = lane >> 3, e = lane & 7;
        #pragma unroll 4
        for (int rr = 0; rr < 32; rr++) {
            int r = wv * 32 + rr;
            float x = mrow[r * 64 + lane];
            float s1 = x, s2 = x * x;
            #pragma unroll
            for (int off = 32; off > 0; off >>= 1) {
                s1 += __shfl_xor(s1, off, 64);
                s2 += __shfl_xor(s2, off, 64);
            }
            float mu  = s1 * (1.0f / 64.0f);
            float var = s2 * (1.0f / 64.0f) - mu * mu;
            float rs  = rsqrtf(var + 1e-5f);
            __hip_bfloat16 mh = __float2bfloat16((x - mu) * rs * gm + bm);
            a_t[r * 64 + ((cl ^ (r & 7)) << 3) + e] = *(short*)&mh;
        }
    }
    __syncthreads();    // drains DMA (vmcnt 0) + LDS writes

    // ---- GEMM: block tile 128 x 512, wave tile 64 x 64 per n-step ----
    const int wm = wv >> 1, wn = wv & 1;

    bf16x8 mf[4][2];    // m̂ A/B-frags, fixed across all n-steps
    #pragma unroll
    for (int mt = 0; mt < 4; mt++) {
        int r = wm * 64 + mt * 16 + col;
        #pragma unroll
        for (int ks = 0; ks < 2; ks++) {
            int c = ks * 4 + quad;
            mf[mt][ks] = *(const bf16x8*)&a_t[r * 64 + ((c ^ (r & 7)) << 3)];
        }
    }

    short* vbase = (short*)v_tg + (size_t)s * 98304;          // [hc][384]
    __hip_bfloat16* gb = g_p + (size_t)s * 98304;             // [384][256]

    #pragma unroll 1
    for (int step = 0; step < 4; step++) {
        bf16x8 wf[4][2];
        #pragma unroll
        for (int nt = 0; nt < 4; nt++) {
            int n = step * 128 + wn * 64 + nt * 16 + col;
            #pragma unroll
            for (int ks = 0; ks < 2; ks++) {
                int c = ks * 4 + quad;
                wf[nt][ks] = *(const bf16x8*)&b_t[n * 64 + ((c ^ (n & 7)) << 3)];
            }
        }

        if (step < 2) {
            // v half: operand-swapped -> D[n][j], matches v_tg transpose
            f32x4 acc[4][4];
            #pragma unroll
            for (int nt = 0; nt < 4; nt++)
                #pragma unroll
                for (int mt = 0; mt < 4; mt++)
                    acc[nt][mt] = (f32x4){0.f, 0.f, 0.f, 0.f};
            #pragma unroll
            for (int ks = 0; ks < 2; ks++)
                #pragma unroll
                for (int nt = 0; nt < 4; nt++)
                    #pragma unroll
                    for (int mt = 0; mt < 4; mt++)
                        acc[nt][mt] = __builtin_amdgcn_mfma_f32_16x16x32_bf16(
                            wf[nt][ks], mf[mt][ks], acc[nt][mt], 0, 0, 0);
            #pragma unroll
            for (int nt = 0; nt < 4; nt++)
                #pragma unroll
                for (int mt = 0; mt < 4; mt++) {
                    int jg = j0 + wm * 64 + mt * 16 + col;
                    #pragma unroll
                    for (int reg = 0; reg < 4; reg++) {
                        int n = step * 128 + wn * 64 + nt * 16 + quad * 4 + reg;
                        __hip_bfloat16 t = __float2bfloat16(acc[nt][mt][reg]);
                        vbase[n * 384 + jg] = *(short*)&t;
                    }
                }
        } else {
            // g half: normal orientation -> D[j][hc]; store with pi^-1 column
            f32x4 acc[4][4];
            #pragma unroll
            for (int mt = 0; mt < 4; mt++)
                #pragma unroll
                for (int nt = 0; nt < 4; nt++)
                    acc[mt][nt] = (f32x4){0.f, 0.f, 0.f, 0.f};
            #pragma unroll
            for (int ks = 0; ks < 2; ks++)
                #pragma unroll
                for (int mt = 0; mt < 4; mt++)
                    #pragma unroll
                    for (int nt = 0; nt < 4; nt++)
                        acc[mt][nt] = __builtin_amdgcn_mfma_f32_16x16x32_bf16(
                            mf[mt][ks], wf[nt][ks], acc[mt][nt], 0, 0, 0);
            #pragma unroll
            for (int mt = 0; mt < 4; mt++)
                #pragma unroll
                for (int nt = 0; nt < 4; nt++) {
                    int n = (step - 2) * 128 + wn * 64 + nt * 16 + col;
                    int c32 = n & 31;
                    int koff = ((c32 & 15) >> 2) * 8 + (c32 & 3)
                             + ((c32 & 16) ? 4 : 0);
                    int kn = (n & ~31) | koff;
                    #pragma unroll
                    for (int reg = 0; reg < 4; reg++) {
                        int jg = j0 + wm * 64 + mt * 16 + quad * 4 + reg;
                        float gv = 1.0f / (1.0f + __expf(-acc[mt][nt][reg]));
                        gb[(size_t)jg * 256 + kn] = __float2bfloat16(gv);
                    }
                }
        }
    }
}

// ---------------------------------------------------------------------------
// k2: 64 rows/block, 4 waves, one wave per row step. grid = 2304.
__global__ __launch_bounds__(256) void k2_ln_z(
    const float* __restrict__ z,
    const float* __restrict__ gamma_z, const float* __restrict__ beta_z,
    const float* __restrict__ W2, float* __restrict__ b_buf)
{
    const int tid = threadIdx.x;
    const int lane = tid & 63, wv = tid >> 6;
    const int R0 = blockIdx.x * 64;
    __shared__ float part[64][9];       // [row_local][h], stride 9 = conflict-free

    float2 g2 = *(const float2*)&gamma_z[lane * 2];
    float2 be2 = *(const float2*)&beta_z[lane * 2];
    float4 w2a = *(const float4*)&W2[lane * 16];
    float4 w2b = *(const float4*)&W2[lane * 16 + 4];
    float4 w2c = *(const float4*)&W2[lane * 16 + 8];
    float4 w2d = *(const float4*)&W2[lane * 16 + 12];

    const bool hi4 = (lane & 4) != 0;
    const bool hi2 = (lane & 2) != 0;
    const bool hi1 = (lane & 1) != 0;

    float2 zx = *(const float2*)&z[(size_t)(R0 + wv * 16) * 128 + lane * 2];
    #pragma unroll 1
    for (int rr = 0; rr < 16; rr++) {
        const int rl = wv * 16 + rr;
        float x0 = zx.x, x1 = zx.y;
        if (rr < 15)
            zx = *(const float2*)&z[(size_t)(R0 + rl + 1) * 128 + lane * 2];

        float s1 = x0 + x1, s2 = x0 * x0 + x1 * x1;
        #pragma unroll
        for (int off = 32; off > 0; off >>= 1) {
            s1 += __shfl_xor(s1, off, 64);
            s2 += __shfl_xor(s2, off, 64);
        }
        float mu  = s1 * (1.0f / 128.0f);
        float var = s2 * (1.0f / 128.0f) - mu * mu;
        float rs  = rsqrtf(var + 1e-5f);
        float mh0 = (x0 - mu) * rs * g2.x + be2.x;
        float mh1 = (x1 - mu) * rs * g2.y + be2.y;

        float p[8];
        p[0] = fmaf(mh0, w2a.x, mh1 * w2c.x);
        p[1] = fmaf(mh0, w2a.y, mh1 * w2c.y);
        p[2] = fmaf(mh0, w2a.z, mh1 * w2c.z);
        p[3] = fmaf(mh0, w2a.w, mh1 * w2c.w);
        p[4] = fmaf(mh0, w2b.x, mh1 * w2d.x);
        p[5] = fmaf(mh0, w2b.y, mh1 * w2d.y);
        p[6] = fmaf(mh0, w2b.z, mh1 * w2d.z);
        p[7] = fmaf(mh0, w2b.w, mh1 * w2d.w);

        float t[4];
        #pragma unroll
        for (int k = 0; k < 4; k++) {
            float keep = hi4 ? p[k + 4] : p[k];
            float send = hi4 ? p[k] : p[k + 4];
            t[k] = keep + __shfl_xor(send, 4, 64);
        }
        float u[2];
        #pragma unroll
        for (int k = 0; k < 2; k++) {
            float keep = hi2 ? t[k + 2] : t[k];
            float send = hi2 ? t[k] : t[k + 2];
            u[k] = keep + __shfl_xor(send, 2, 64);
        }
        float vsum;
        {
            float keep = hi1 ? u[1] : u[0];
            float send = hi1 ? u[0] : u[1];
            vsum = keep + __shfl_xor(send, 1, 64);
        }
        vsum += __shfl_xor(vsum, 8, 64);
        vsum += __shfl_xor(vsum, 16, 64);
        vsum += __shfl_xor(vsum, 32, 64);
        if (lane < 8) part[rl][lane] = vsum;   // h = lane
    }
    __syncthreads();

    {
        int h0 = tid >> 6, rl = tid & 63;
        b_buf[(size_t)h0 * 147456 + R0 + rl]       = part[rl][h0];
        b_buf[(size_t)(h0 + 4) * 147456 + R0 + rl] = part[rl][h0 + 4];
    }
}

// ---------------------------------------------------------------------------
// k3a: partial online softmax over 16-i chunks. grid = 8*24 = 192, block 128.
__global__ __launch_bounds__(128) void k3a_part(
    const float* __restrict__ w_buf, float* __restrict__ pm, float* __restrict__ pl)
{
    const int h = blockIdx.x / 24, ic = blockIdx.x % 24;
    const int i0 = ic * 16;
    const int tid = threadIdx.x;
    const float* base = w_buf + ((size_t)h * 384 + i0) * 384;

    float m0 = -INFINITY, m1 = -INFINITY, m2 = -INFINITY;
    float l0 = 0.f, l1 = 0.f, l2 = 0.f;
    #pragma unroll 4
    for (int ii = 0; ii < 16; ii++) {
        float x0 = base[ii * 384 + tid];
        float x1 = base[ii * 384 + tid + 128];
        float x2 = base[ii * 384 + tid + 256];
        float n0 = fmaxf(m0, x0);
        l0 = l0 * __expf(m0 - n0) + __expf(x0 - n0); m0 = n0;
        float n1 = fmaxf(m1, x1);
        l1 = l1 * __expf(m1 - n1) + __expf(x1 - n1); m1 = n1;
        float n2 = fmaxf(m2, x2);
        l2 = l2 * __expf(m2 - n2) + __expf(x2 - n2); m2 = n2;
    }
    float* pmb = pm + ((size_t)h * 24 + ic) * 384;
    float* plb = pl + ((size_t)h * 24 + ic) * 384;
    pmb[tid]       = m0;  plb[tid]       = l0;
    pmb[tid + 128] = m1;  plb[tid + 128] = l1;
    pmb[tid + 256] = m2;  plb[tid + 256] = l2;
}

// k3m: combine 24 partials -> M, invL. grid = 8 blocks, 384 threads.
__global__ __launch_bounds__(384) void k3m_comb(
    const float* __restrict__ pm, const float* __restrict__ pl,
    float* __restrict__ Mf, float* __restrict__ invLf)
{
    const int h = blockIdx.x, j = threadIdx.x;
    float M = -INFINITY, L = 0.f;
    #pragma unroll 4
    for (int ic = 0; ic < 24; ic++) {
        float m = pm[((size_t)h * 24 + ic) * 384 + j];
        float l = pl[((size_t)h * 24 + ic) * 384 + j];
        float nM = fmaxf(M, m);
        L = L * __expf(M - nM) + l * __expf(m - nM);
        M = nM;
    }
    Mf[h * 384 + j] = M;
    invLf[h * 384 + j] = 1.0f / L;
}

// k3b: write normalized bf16 weights. grid = 192, block 128.
__global__ __launch_bounds__(128) void k3b_write(
    const float* __restrict__ w_buf, const float* __restrict__ Mf,
    const float* __restrict__ invLf, __hip_bfloat16* __restrict__ w_bf)
{
    const int h = blockIdx.x / 24, ic = blockIdx.x % 24;
    const int i0 = ic * 16;
    const int tid = threadIdx.x;
    const float* base = w_buf + ((size_t)h * 384 + i0) * 384;
    __hip_bfloat16* ob = w_bf + ((size_t)h * 384 + i0) * 384;

    float M0 = Mf[h * 384 + tid],       iL0 = invLf[h * 384 + tid];
    float M1 = Mf[h * 384 + tid + 128], iL1 = invLf[h * 384 + tid + 128];
    float M2 = Mf[h * 384 + tid + 256], iL2 = invLf[h * 384 + tid + 256];
    #pragma unroll 4
    for (int ii = 0; ii < 16; ii++) {
        float x0 = base[ii * 384 + tid];
        float x1 = base[ii * 384 + tid + 128];
        float x2 = base[ii * 384 + tid + 256];
        ob[ii * 384 + tid]       = __float2bfloat16(__expf(x0 - M0) * iL0);
        ob[ii * 384 + tid + 128] = __float2bfloat16(__expf(x1 - M1) * iL1);
        ob[ii * 384 + tid + 256] = __float2bfloat16(__expf(x2 - M2) * iL2);
    }
}

// ---------------------------------------------------------------------------
// k4: MFMA einsum + gate + @W4.  grid = 512*6 = 3072 blocks, 256 threads.
//
// R6 = R5 structure with the spill fixed: per-h accumulators are gated and
// packed to bf16 paf[h] (4 VGPRs) IMMEDIATELY after the h's MFMA cluster.
// Live state peak ~140 VGPRs < 168 cap at 3 blocks/CU -> no scratch.
__global__ __launch_bounds__(256, 3) void k4_mfma(
    const __hip_bfloat16* __restrict__ w_bf,   // [8][384 i][384 j]
    const __hip_bfloat16* __restrict__ v_tg,   // [512][8][32 c][384 j]
    const __hip_bfloat16* __restrict__ g_p,    // [512][384 i][256 k(pi)]
    const __hip_bfloat16* __restrict__ W4p,    // [64 d][256 k(pi)]
    float* __restrict__ out)                   // [512][384][64]
{
    __shared__ short v_t[2][12288];            // 2 x 24576 B: [32 c][384 j]
    const int bx0 = blockIdx.x;
    const int bx = (bx0 & 7) * 384 + (bx0 >> 3);   // bijective XCD swizzle
    const int s = bx / 6, i0 = (bx % 6) * 64;
    const int tid = threadIdx.x;
    const int lane = tid & 63, wv = tid >> 6;
    const int col = lane & 15, quad = lane >> 4;
    const int swz = col & 7;

    // stage geometry: 1536 16B-chunks; chunk p = r*256 + tid; row = p/48;
    // source chunk = (p%48) ^ (row&7)  (inverse swizzle on global source)
    int srow[6], skc[6];
    #pragma unroll
    for (int r = 0; r < 6; r++) {
        int p = r * 256 + tid;
        int row = p / 48;
        srow[r] = row;
        skc[r] = (p - row * 48) ^ (row & 7);
    }

    const short* vslab = (const short*)v_tg + (size_t)s * 98304;
    const short* wbase = (const short*)w_bf
        + (size_t)(i0 + wv * 16 + col) * 384 + quad * 8;

    auto STAGE = [&](int buf, int hh) {
        const short* src = vslab + hh * 12288;
        #pragma unroll
        for (int r = 0; r < 6; r++) {
            __builtin_amdgcn_global_load_lds(
                (const __attribute__((address_space(1))) u32*)
                    (src + srow[r] * 384 + skc[r] * 8),
                (__attribute__((address_space(3))) u32*)
                    (&v_t[buf][r * 2048 + wv * 512]),
                16, 0, 0);
        }
    };

    // prologue: gates (latency hides under the h-loop) + first V stage
    const short* gbase = (const short*)g_p
        + (size_t)(s * 384 + i0 + wv * 16 + col) * 256 + quad * 8;
    bf16x8 gf[8];
    #pragma unroll
    for (int h = 0; h < 8; h++)
        gf[h] = *(const bf16x8*)(gbase + h * 32);

    STAGE(0, 0);

    bf16x8 paf[8];      // gated bf16 A-frags for the W4 GEMM (4 VGPRs each)

    #pragma unroll
    for (int h = 0; h < 8; h++) {
        __builtin_amdgcn_sched_barrier(0);
        asm volatile("s_waitcnt vmcnt(0)" ::: "memory");   // own S(h) done
        __builtin_amdgcn_s_barrier();                      // everyone's S(h)
        __builtin_amdgcn_sched_barrier(0);

        // W fragments for this h: issue BEFORE the stage so the compiler's
        // waits for them leave the S(h+1) prefetch in flight.
        bf16x8 wf[12];
        const short* wA = wbase + (size_t)h * 147456;
        #pragma unroll
        for (int ks = 0; ks < 12; ks++)
            wf[ks] = *(const bf16x8*)(wA + ks * 32);

        if (h < 7) STAGE((h + 1) & 1, h + 1);

        f32x4 a0v = {0.f, 0.f, 0.f, 0.f}, a1v = {0.f, 0.f, 0.f, 0.f};
        __builtin_amdgcn_s_setprio(1);
        #pragma unroll
        for (int ks = 0; ks < 12; ks++) {
            int ch = (ks * 4 + quad) ^ swz;
            bf16x8 a0 = *(const bf16x8*)&v_t[h & 1][col * 384 + ch * 8];
            bf16x8 a1 = *(const bf16x8*)&v_t[h & 1][(16 + col) * 384 + ch * 8];
            a0v = __builtin_amdgcn_mfma_f32_16x16x32_bf16(a0, wf[ks], a0v, 0, 0, 0);
            a1v = __builtin_amdgcn_mfma_f32_16x16x32_bf16(a1, wf[ks], a1v, 0, 0, 0);
        }
        __builtin_amdgcn_s_setprio(0);

        // gate + pack NOW: frees the f32 accumulators (anti-spill, rule #20)
        #pragma unroll
        for (int e = 0; e < 4; e++) {
            float v0 = a0v[e] * b2f(gf[h][e]);
            float v1 = a1v[e] * b2f(gf[h][4 + e]);
            __hip_bfloat16 t0 = __float2bfloat16(v0);
            __hip_bfloat16 t1 = __float2bfloat16(v1);
            paf[h][e]     = *(short*)&t0;
            paf[h][4 + e] = *(short*)&t1;
        }
    }

    // epilogue: W4 GEMM straight from registers, store.
    f32x4 acc2[4];
    #pragma unroll
    for (int n = 0; n < 4; n++) acc2[n] = (f32x4){0.f, 0.f, 0.f, 0.f};
    #pragma unroll
    for (int h = 0; h < 8; h++) {
        #pragma unroll
        for (int n = 0; n < 4; n++) {
            bf16x8 b = *(const bf16x8*)((const short*)W4p
                        + (n * 16 + col) * 256 + h * 32 + quad * 8);
            acc2[n] = __builtin_amdgcn_mfma_f32_16x16x32_bf16(
                          paf[h], b, acc2[n], 0, 0, 0);
        }
    }
    float* obase = out + (size_t)(s * 384 + i0 + wv * 16 + quad * 4) * 64;
    #pragma unroll
    for (int n = 0; n < 4; n++)
        #pragma unroll
        for (int reg = 0; reg < 4; reg++)
            obase[reg * 64 + n * 16 + col] = acc2[n][reg];
}

// ---------------------------------------------------------------------------
extern "C" void kernel_launch(void* const* d_in, const int* in_sizes, int n_in,
                              void* d_out, int out_size, void* d_ws, size_t ws_size,
                              hipStream_t stream)
{
    const float* m_si    = (const float*)d_in[0];
    const float* z_ij    = (const float*)d_in[1];
    const float* gamma_m = (const float*)d_in[2];
    const float* beta_m  = (const float*)d_in[3];
    const float* W1      = (const float*)d_in[4];
    const float* gamma_z = (const float*)d_in[5];
    const float* beta_z  = (const float*)d_in[6];
    const float* W2      = (const float*)d_in[7];
    const float* W3      = (const float*)d_in[8];
    const float* W4      = (const float*)d_in[9];
    float* out = (float*)d_out;

    // ws layout (~209.0 MB):
    //   g_p  : 100663296 B   v_tg : 100663296 B   w_buf(fp32): 4718592 B
    //   w_bf : 2359296 B     W4p  : 32768 B
    //   pm/pl: 294912 B each   Mf/invLf: 12288 B each
    //   W13s : 65536 B, ALIASES w_buf (dead until k2; k1 reads before k2 writes)
    char* ws = (char*)d_ws;
    __hip_bfloat16* g_p  = (__hip_bfloat16*)ws;
    __hip_bfloat16* v_tg = (__hip_bfloat16*)(ws + 100663296);
    float*          w_buf = (float*)(ws + 201326592);
    __hip_bfloat16* W13s = (__hip_bfloat16*)(ws + 201326592);  // alias w_buf
    __hip_bfloat16* w_bf = (__hip_bfloat16*)(ws + 206045184);
    __hip_bfloat16* W4p  = (__hip_bfloat16*)(ws + 208404480);
    float* pm    = (float*)(ws + 208437248);
    float* pl    = (float*)(ws + 208732160);
    float* Mf    = (float*)(ws + 209027072);
    float* invLf = (float*)(ws + 209039360);

    k0_prep  <<<192,  256, 0, stream>>>(W4, W1, W3, W4p, W13s);
    k1_ln_mv <<<1536, 256, 0, stream>>>(m_si, gamma_m, beta_m, W13s, v_tg, g_p);
    k2_ln_z  <<<2304, 256, 0, stream>>>(z_ij, gamma_z, beta_z, W2, w_buf);
    k3a_part <<<192,  128, 0, stream>>>(w_buf, pm, pl);
    k3m_comb <<<8,    384, 0, stream>>>(pm, pl, Mf, invLf);
    k3b_write<<<192,  128, 0, stream>>>(w_buf, Mf, invLf, w_bf);
    k4_mfma  <<<3072, 256, 0, stream>>>(w_bf, v_tg, g_p, W4p, out);
}

// Round 7
// 493.603 us; speedup vs baseline: 1.1147x; 1.0461x over previous
//
#include <hip/hip_runtime.h>
#include <hip/hip_bf16.h>
#include <math.h>

// Shapes: B=1, S=512, N=384, c_m=64, c_z=128, H=8, c=32  (HC = 256)
//
// Pipeline:
//  k0_prep: W4 -> W4p[64][256] bf16 with pi-PERMUTED k axis (see below);
//           W1|W3 -> W13s[512][64] bf16 chunk-swizzled for k1's DMA.
//  k1     : m = LN(m_si) -> bf16 LDS; MFMA GEMM vs W13 (K=64):
//           v = m@W1 stored TRANSPOSED v_tg[s][hc][j];
//           g = sigmoid(m@W3) -> g_p[s][j][k] with pi-permuted k columns.
//  k2     : b = LN(z)@W2 -> w_buf[h][i][j] fp32
//  k3a/m/b: softmax over i -> w_bf[h][i][j] bf16
//  k4     : operand-swapped MFMA einsum + in-register gate + W4 GEMM.
//           R7: correct-FIFO 3-buffer async pipeline (see k4 comment).
//
// pi(32h + quad*8 + e) = 32h + (e<4 ? quad*4+e : 16 + quad*4 + (e-4))

typedef __attribute__((ext_vector_type(8))) short bf16x8;   // 8 bf16 = 4 VGPRs
typedef __attribute__((ext_vector_type(4))) float f32x4;
typedef unsigned int u32;

__device__ inline float b2f(short v) {
    union { float f; u32 u; } t; t.u = ((u32)(unsigned short)v) << 16; return t.f;
}

__global__ __launch_bounds__(256) void k0_prep(
    const float* __restrict__ W4, const float* __restrict__ W1,
    const float* __restrict__ W3,
    __hip_bfloat16* __restrict__ W4p,    // [64 d][256 k]  k = pi-permuted hc
    __hip_bfloat16* __restrict__ W13s)   // [512][64] chunk-swizzled
{
    int idx = blockIdx.x * 256 + threadIdx.x;   // 192*256 = 49152
    if (idx < 16384) {
        int d = idx >> 8, k = idx & 255;
        int koff = k & 31, h = k >> 5;
        int quad = koff >> 3, e = koff & 7;
        int c = (e < 4) ? (quad * 4 + e) : (16 + quad * 4 + (e - 4));
        int hc = h * 32 + c;
        W4p[idx] = __float2bfloat16(W4[hc * 64 + d]);
    } else {
        int t = idx - 16384;            // 0..32767
        int n = t >> 6, k = t & 63;
        float v = (n < 256) ? W1[k * 256 + n] : W3[k * 256 + (n - 256)];
        int dst = n * 64 + ((((k >> 3) ^ (n & 7))) << 3) + (k & 7);
        W13s[dst] = __float2bfloat16(v);
    }
}

// ---------------------------------------------------------------------------
// k1: LN + dual GEMM via MFMA. grid = 512*3 = 1536 blocks, 256 threads.
__global__ __launch_bounds__(256) void k1_ln_mv(
    const float* __restrict__ m_si,
    const float* __restrict__ gamma_m, const float* __restrict__ beta_m,
    const __hip_bfloat16* __restrict__ W13s, // [512][64] bf16 pre-swizzled
    __hip_bfloat16* __restrict__ v_tg,   // [512][256 hc][384 j]
    __hip_bfloat16* __restrict__ g_p)    // [512][384 j][256 k(pi)]
{
    __shared__ short a_t[128 * 64];     // 16384 B: m̂, chunk-swizzled
    __shared__ short b_t[512 * 64];     // 65536 B: W13, chunk-swizzled
    const int bx = blockIdx.x;
    const int s = bx / 3, j0 = (bx % 3) * 128;
    const int tid = threadIdx.x;
    const int lane = tid & 63, wv = tid >> 6;
    const int col = lane & 15, quad = lane >> 4;

    // ---- stage W13 into LDS (async DMA; overlaps the LN VALU phase) ----
    {
        const short* src = (const short*)W13s;
        #pragma unroll
        for (int i = 0; i < 16; i++) {
            __builtin_amdgcn_global_load_lds(
                (const __attribute__((address_space(1))) u32*)
                    (src + i * 2048 + wv * 512 + lane * 8),
                (__attribute__((address_space(3))) u32*)(b_t + i * 2048 + wv * 512),
                16, 0, 0);
        }
    }

    // ---- LN: 32 rows per wave, lane = channel; write bf16 m̂ swizzled ----
    {
        const float gm = gamma_m[lane], bm = beta_m[lane];
        const float* mrow = m_si + (size_t)(s * 384 + j0) * 64;
        const int cl = lane >> 3, e = lane & 7;
        #pragma unroll 4
        for (int rr = 0; rr < 32; rr++) {
            int r = wv * 32 + rr;
            float x = mrow[r * 64 + lane];
            float s1 = x, s2 = x * x;
            #pragma unroll
            for (int off = 32; off > 0; off >>= 1) {
                s1 += __shfl_xor(s1, off, 64);
                s2 += __shfl_xor(s2, off, 64);
            }
            float mu  = s1 * (1.0f / 64.0f);
            float var = s2 * (1.0f / 64.0f) - mu * mu;
            float rs  = rsqrtf(var + 1e-5f);
            __hip_bfloat16 mh = __float2bfloat16((x - mu) * rs * gm + bm);
            a_t[r * 64 + ((cl ^ (r & 7)) << 3) + e] = *(short*)&mh;
        }
    }
    __syncthreads();    // drains DMA (vmcnt 0) + LDS writes

    // ---- GEMM: block tile 128 x 512, wave tile 64 x 64 per n-step ----
    const int wm = wv >> 1, wn = wv & 1;

    bf16x8 mf[4][2];    // m̂ A/B-frags, fixed across all n-steps
    #pragma unroll
    for (int mt = 0; mt < 4; mt++) {
        int r = wm * 64 + mt * 16 + col;
        #pragma unroll
        for (int ks = 0; ks < 2; ks++) {
            int c = ks * 4 + quad;
            mf[mt][ks] = *(const bf16x8*)&a_t[r * 64 + ((c ^ (r & 7)) << 3)];
        }
    }

    short* vbase = (short*)v_tg + (size_t)s * 98304;          // [hc][384]
    __hip_bfloat16* gb = g_p + (size_t)s * 98304;             // [384][256]

    #pragma unroll 1
    for (int step = 0; step < 4; step++) {
        bf16x8 wf[4][2];
        #pragma unroll
        for (int nt = 0; nt < 4; nt++) {
            int n = step * 128 + wn * 64 + nt * 16 + col;
            #pragma unroll
            for (int ks = 0; ks < 2; ks++) {
                int c = ks * 4 + quad;
                wf[nt][ks] = *(const bf16x8*)&b_t[n * 64 + ((c ^ (n & 7)) << 3)];
            }
        }

        if (step < 2) {
            // v half: operand-swapped -> D[n][j], matches v_tg transpose
            f32x4 acc[4][4];
            #pragma unroll
            for (int nt = 0; nt < 4; nt++)
                #pragma unroll
                for (int mt = 0; mt < 4; mt++)
                    acc[nt][mt] = (f32x4){0.f, 0.f, 0.f, 0.f};
            #pragma unroll
            for (int ks = 0; ks < 2; ks++)
                #pragma unroll
                for (int nt = 0; nt < 4; nt++)
                    #pragma unroll
                    for (int mt = 0; mt < 4; mt++)
                        acc[nt][mt] = __builtin_amdgcn_mfma_f32_16x16x32_bf16(
                            wf[nt][ks], mf[mt][ks], acc[nt][mt], 0, 0, 0);
            #pragma unroll
            for (int nt = 0; nt < 4; nt++)
                #pragma unroll
                for (int mt = 0; mt < 4; mt++) {
                    int jg = j0 + wm * 64 + mt * 16 + col;
                    #pragma unroll
                    for (int reg = 0; reg < 4; reg++) {
                        int n = step * 128 + wn * 64 + nt * 16 + quad * 4 + reg;
                        __hip_bfloat16 t = __float2bfloat16(acc[nt][mt][reg]);
                        vbase[n * 384 + jg] = *(short*)&t;
                    }
                }
        } else {
            // g half: normal orientation -> D[j][hc]; store with pi^-1 column
            f32x4 acc[4][4];
            #pragma unroll
            for (int mt = 0; mt < 4; mt++)
                #pragma unroll
                for (int nt = 0; nt < 4; nt++)
                    acc[mt][nt] = (f32x4){0.f, 0.f, 0.f, 0.f};
            #pragma unroll
            for (int ks = 0; ks < 2; ks++)
                #pragma unroll
                for (int mt = 0; mt < 4; mt++)
                    #pragma unroll
                    for (int nt = 0; nt < 4; nt++)
                        acc[mt][nt] = __builtin_amdgcn_mfma_f32_16x16x32_bf16(
                            mf[mt][ks], wf[nt][ks], acc[mt][nt], 0, 0, 0);
            #pragma unroll
            for (int mt = 0; mt < 4; mt++)
                #pragma unroll
                for (int nt = 0; nt < 4; nt++) {
                    int n = (step - 2) * 128 + wn * 64 + nt * 16 + col;
                    int c32 = n & 31;
                    int koff = ((c32 & 15) >> 2) * 8 + (c32 & 3)
                             + ((c32 & 16) ? 4 : 0);
                    int kn = (n & ~31) | koff;
                    #pragma unroll
                    for (int reg = 0; reg < 4; reg++) {
                        int jg = j0 + wm * 64 + mt * 16 + quad * 4 + reg;
                        float gv = 1.0f / (1.0f + __expf(-acc[mt][nt][reg]));
                        gb[(size_t)jg * 256 + kn] = __float2bfloat16(gv);
                    }
                }
        }
    }
}

// ---------------------------------------------------------------------------
// k2: 64 rows/block, 4 waves, one wave per row step. grid = 2304.
__global__ __launch_bounds__(256) void k2_ln_z(
    const float* __restrict__ z,
    const float* __restrict__ gamma_z, const float* __restrict__ beta_z,
    const float* __restrict__ W2, float* __restrict__ b_buf)
{
    const int tid = threadIdx.x;
    const int lane = tid & 63, wv = tid >> 6;
    const int R0 = blockIdx.x * 64;
    __shared__ float part[64][9];       // [row_local][h], stride 9 = conflict-free

    float2 g2 = *(const float2*)&gamma_z[lane * 2];
    float2 be2 = *(const float2*)&beta_z[lane * 2];
    float4 w2a = *(const float4*)&W2[lane * 16];
    float4 w2b = *(const float4*)&W2[lane * 16 + 4];
    float4 w2c = *(const float4*)&W2[lane * 16 + 8];
    float4 w2d = *(const float4*)&W2[lane * 16 + 12];

    const bool hi4 = (lane & 4) != 0;
    const bool hi2 = (lane & 2) != 0;
    const bool hi1 = (lane & 1) != 0;

    float2 zx = *(const float2*)&z[(size_t)(R0 + wv * 16) * 128 + lane * 2];
    #pragma unroll 1
    for (int rr = 0; rr < 16; rr++) {
        const int rl = wv * 16 + rr;
        float x0 = zx.x, x1 = zx.y;
        if (rr < 15)
            zx = *(const float2*)&z[(size_t)(R0 + rl + 1) * 128 + lane * 2];

        float s1 = x0 + x1, s2 = x0 * x0 + x1 * x1;
        #pragma unroll
        for (int off = 32; off > 0; off >>= 1) {
            s1 += __shfl_xor(s1, off, 64);
            s2 += __shfl_xor(s2, off, 64);
        }
        float mu  = s1 * (1.0f / 128.0f);
        float var = s2 * (1.0f / 128.0f) - mu * mu;
        float rs  = rsqrtf(var + 1e-5f);
        float mh0 = (x0 - mu) * rs * g2.x + be2.x;
        float mh1 = (x1 - mu) * rs * g2.y + be2.y;

        float p[8];
        p[0] = fmaf(mh0, w2a.x, mh1 * w2c.x);
        p[1] = fmaf(mh0, w2a.y, mh1 * w2c.y);
        p[2] = fmaf(mh0, w2a.z, mh1 * w2c.z);
        p[3] = fmaf(mh0, w2a.w, mh1 * w2c.w);
        p[4] = fmaf(mh0, w2b.x, mh1 * w2d.x);
        p[5] = fmaf(mh0, w2b.y, mh1 * w2d.y);
        p[6] = fmaf(mh0, w2b.z, mh1 * w2d.z);
        p[7] = fmaf(mh0, w2b.w, mh1 * w2d.w);

        float t[4];
        #pragma unroll
        for (int k = 0; k < 4; k++) {
            float keep = hi4 ? p[k + 4] : p[k];
            float send = hi4 ? p[k] : p[k + 4];
            t[k] = keep + __shfl_xor(send, 4, 64);
        }
        float u[2];
        #pragma unroll
        for (int k = 0; k < 2; k++) {
            float keep = hi2 ? t[k + 2] : t[k];
            float send = hi2 ? t[k] : t[k + 2];
            u[k] = keep + __shfl_xor(send, 2, 64);
        }
        float vsum;
        {
            float keep = hi1 ? u[1] : u[0];
            float send = hi1 ? u[0] : u[1];
            vsum = keep + __shfl_xor(send, 1, 64);
        }
        vsum += __shfl_xor(vsum, 8, 64);
        vsum += __shfl_xor(vsum, 16, 64);
        vsum += __shfl_xor(vsum, 32, 64);
        if (lane < 8) part[rl][lane] = vsum;   // h = lane
    }
    __syncthreads();

    {
        int h0 = tid >> 6, rl = tid & 63;
        b_buf[(size_t)h0 * 147456 + R0 + rl]       = part[rl][h0];
        b_buf[(size_t)(h0 + 4) * 147456 + R0 + rl] = part[rl][h0 + 4];
    }
}

// ---------------------------------------------------------------------------
// k3a: partial online softmax over 16-i chunks. grid = 8*24 = 192, block 128.
__global__ __launch_bounds__(128) void k3a_part(
    const float* __restrict__ w_buf, float* __restrict__ pm, float* __restrict__ pl)
{
    const int h = blockIdx.x / 24, ic = blockIdx.x % 24;
    const int i0 = ic * 16;
    const int tid = threadIdx.x;
    const float* base = w_buf + ((size_t)h * 384 + i0) * 384;

    float m0 = -INFINITY, m1 = -INFINITY, m2 = -INFINITY;
    float l0 = 0.f, l1 = 0.f, l2 = 0.f;
    #pragma unroll 4
    for (int ii = 0; ii < 16; ii++) {
        float x0 = base[ii * 384 + tid];
        float x1 = base[ii * 384 + tid + 128];
        float x2 = base[ii * 384 + tid + 256];
        float n0 = fmaxf(m0, x0);
        l0 = l0 * __expf(m0 - n0) + __expf(x0 - n0); m0 = n0;
        float n1 = fmaxf(m1, x1);
        l1 = l1 * __expf(m1 - n1) + __expf(x1 - n1); m1 = n1;
        float n2 = fmaxf(m2, x2);
        l2 = l2 * __expf(m2 - n2) + __expf(x2 - n2); m2 = n2;
    }
    float* pmb = pm + ((size_t)h * 24 + ic) * 384;
    float* plb = pl + ((size_t)h * 24 + ic) * 384;
    pmb[tid]       = m0;  plb[tid]       = l0;
    pmb[tid + 128] = m1;  plb[tid + 128] = l1;
    pmb[tid + 256] = m2;  plb[tid + 256] = l2;
}

// k3m: combine 24 partials -> M, invL. grid = 8 blocks, 384 threads.
__global__ __launch_bounds__(384) void k3m_comb(
    const float* __restrict__ pm, const float* __restrict__ pl,
    float* __restrict__ Mf, float* __restrict__ invLf)
{
    const int h = blockIdx.x, j = threadIdx.x;
    float M = -INFINITY, L = 0.f;
    #pragma unroll 4
    for (int ic = 0; ic < 24; ic++) {
        float m = pm[((size_t)h * 24 + ic) * 384 + j];
        float l = pl[((size_t)h * 24 + ic) * 384 + j];
        float nM = fmaxf(M, m);
        L = L * __expf(M - nM) + l * __expf(m - nM);
        M = nM;
    }
    Mf[h * 384 + j] = M;
    invLf[h * 384 + j] = 1.0f / L;
}

// k3b: write normalized bf16 weights. grid = 192, block 128.
__global__ __launch_bounds__(128) void k3b_write(
    const float* __restrict__ w_buf, const float* __restrict__ Mf,
    const float* __restrict__ invLf, __hip_bfloat16* __restrict__ w_bf)
{
    const int h = blockIdx.x / 24, ic = blockIdx.x % 24;
    const int i0 = ic * 16;
    const int tid = threadIdx.x;
    const float* base = w_buf + ((size_t)h * 384 + i0) * 384;
    __hip_bfloat16* ob = w_bf + ((size_t)h * 384 + i0) * 384;

    float M0 = Mf[h * 384 + tid],       iL0 = invLf[h * 384 + tid];
    float M1 = Mf[h * 384 + tid + 128], iL1 = invLf[h * 384 + tid + 128];
    float M2 = Mf[h * 384 + tid + 256], iL2 = invLf[h * 384 + tid + 256];
    #pragma unroll 4
    for (int ii = 0; ii < 16; ii++) {
        float x0 = base[ii * 384 + tid];
        float x1 = base[ii * 384 + tid + 128];
        float x2 = base[ii * 384 + tid + 256];
        ob[ii * 384 + tid]       = __float2bfloat16(__expf(x0 - M0) * iL0);
        ob[ii * 384 + tid + 128] = __float2bfloat16(__expf(x1 - M1) * iL1);
        ob[ii * 384 + tid + 256] = __float2bfloat16(__expf(x2 - M2) * iL2);
    }
}

// ---------------------------------------------------------------------------
// k4: MFMA einsum + gate + @W4.  grid = 512*6 = 3072 blocks, 256 threads.
//
// R7: correct-FIFO 3-buffer pipeline. Post-mortem R3-R6: every variant had
// effective prefetch depth <= half a phase (vmcnt(0) drains, or loads issued
// after the stage forced the compiler's wait to drain it). Fix:
//  - 3 V buffers; STAGE(h+2) issued in phase h -> ~1.5 phases in flight.
//  - Per-phase issue order = consumption order: [wf(12), gf(2)] then
//    [STAGE(h+2)(6)] then explicit s_waitcnt vmcnt(8): drains exactly wf and
//    S(h+1) (a full phase old), leaves gf + S(h+2) in flight. NO vmcnt(0)
//    anywhere in the loop.
//  - No entry wait needed: each wave's previous-phase vmcnt(8) drained its
//    own S(h) DMA ops; the end-of-phase s_barrier publishes them to all
//    waves before any buf(h) read. STAGE(h+2) overwrites buf(h-1), whose
//    readers all passed the phase-(h-1) end barrier. Verified per-wave.
//  - gf de-hoisted (4 live VGPRs, compiler waits vmcnt(6) before pack,
//    leaving the stage in flight). launch_bounds(256,2): 256-VGPR budget,
//    no spill (R5/R6 spill marker: WRITE_SIZE must drop to ~49 MB).
//  - LDS 3 x 24576 = 73728 B -> 2 blocks/CU (LDS-bound by design).
__global__ __launch_bounds__(256, 2) void k4_mfma(
    const __hip_bfloat16* __restrict__ w_bf,   // [8][384 i][384 j]
    const __hip_bfloat16* __restrict__ v_tg,   // [512][8][32 c][384 j]
    const __hip_bfloat16* __restrict__ g_p,    // [512][384 i][256 k(pi)]
    const __hip_bfloat16* __restrict__ W4p,    // [64 d][256 k(pi)]
    float* __restrict__ out)                   // [512][384][64]
{
    __shared__ short v_t[3][12288];            // 3 x 24576 B: [32 c][384 j]
    const int bx0 = blockIdx.x;
    const int bx = (bx0 & 7) * 384 + (bx0 >> 3);   // bijective XCD swizzle
    const int s = bx / 6, i0 = (bx % 6) * 64;
    const int tid = threadIdx.x;
    const int lane = tid & 63, wv = tid >> 6;
    const int col = lane & 15, quad = lane >> 4;
    const int swz = col & 7;

    // stage geometry: 1536 16B-chunks; chunk p = r*256 + tid; row = p/48;
    // source chunk = (p%48) ^ (row&7)  (inverse swizzle on global source)
    int srow[6], skc[6];
    #pragma unroll
    for (int r = 0; r < 6; r++) {
        int p = r * 256 + tid;
        int row = p / 48;
        srow[r] = row;
        skc[r] = (p - row * 48) ^ (row & 7);
    }

    const short* vslab = (const short*)v_tg + (size_t)s * 98304;
    const short* wbase = (const short*)w_bf
        + (size_t)(i0 + wv * 16 + col) * 384 + quad * 8;
    const short* gbase = (const short*)g_p
        + (size_t)(s * 384 + i0 + wv * 16 + col) * 256 + quad * 8;

    auto STAGE = [&](int buf, int hh) {
        const short* src = vslab + hh * 12288;
        #pragma unroll
        for (int r = 0; r < 6; r++) {
            __builtin_amdgcn_global_load_lds(
                (const __attribute__((address_space(1))) u32*)
                    (src + srow[r] * 384 + skc[r] * 8),
                (__attribute__((address_space(3))) u32*)
                    (&v_t[buf][r * 2048 + wv * 512]),
                16, 0, 0);
        }
    };

    // prologue: S(0), S(1); drain S(0) only; publish.
    STAGE(0, 0);
    STAGE(1, 1);
    asm volatile("s_waitcnt vmcnt(6)" ::: "memory");
    __builtin_amdgcn_s_barrier();

    bf16x8 paf[8];      // gated bf16 A-frags for the W4 GEMM (4 VGPRs each)

    #pragma unroll
    for (int h = 0; h < 8; h++) {
        __builtin_amdgcn_sched_barrier(0);
        // group 1: loads consumed THIS phase (wf for MFMA, gf for pack)
        bf16x8 wf[12];
        const short* wA = wbase + (size_t)h * 147456;
        #pragma unroll
        for (int ks = 0; ks < 12; ks++)
            wf[ks] = *(const bf16x8*)(wA + ks * 32);
        bf16x8 gfh = *(const bf16x8*)(gbase + h * 32);
        __builtin_amdgcn_sched_barrier(0);
        // group 2: prefetch consumed at phase h+2
        if (h < 6) STAGE((h + 2) % 3, h + 2);
        __builtin_amdgcn_sched_barrier(0);
        // drain wf + S(h+1) (full phase old); keep gf + S(h+2) in flight
        if (h < 6) asm volatile("s_waitcnt vmcnt(8)" ::: "memory");
        else       asm volatile("s_waitcnt vmcnt(2)" ::: "memory");
        __builtin_amdgcn_sched_barrier(0);

        f32x4 a0v = {0.f, 0.f, 0.f, 0.f}, a1v = {0.f, 0.f, 0.f, 0.f};
        __builtin_amdgcn_s_setprio(1);
        #pragma unroll
        for (int ks = 0; ks < 12; ks++) {
            int ch = (ks * 4 + quad) ^ swz;
            bf16x8 a0 = *(const bf16x8*)&v_t[h % 3][col * 384 + ch * 8];
            bf16x8 a1 = *(const bf16x8*)&v_t[h % 3][(16 + col) * 384 + ch * 8];
            a0v = __builtin_amdgcn_mfma_f32_16x16x32_bf16(a0, wf[ks], a0v, 0, 0, 0);
            a1v = __builtin_amdgcn_mfma_f32_16x16x32_bf16(a1, wf[ks], a1v, 0, 0, 0);
        }
        __builtin_amdgcn_s_setprio(0);

        // gate + pack NOW (frees f32 accs; compiler waits gf leaving stage)
        #pragma unroll
        for (int e = 0; e < 4; e++) {
            float v0 = a0v[e] * b2f(gfh[e]);
            float v1 = a1v[e] * b2f(gfh[4 + e]);
            __hip_bfloat16 t0 = __float2bfloat16(v0);
            __hip_bfloat16 t1 = __float2bfloat16(v1);
            paf[h][e]     = *(short*)&t0;
            paf[h][4 + e] = *(short*)&t1;
        }
        // end-of-phase barrier: publishes S(h+1) drains + protects buf(h)
        // from phase-(h+1)'s STAGE(h+3) overwrite.
        if (h < 7) __builtin_amdgcn_s_barrier();
    }

    // epilogue: W4 GEMM straight from registers, store.
    f32x4 acc2[4];
    #pragma unroll
    for (int n = 0; n < 4; n++) acc2[n] = (f32x4){0.f, 0.f, 0.f, 0.f};
    #pragma unroll
    for (int h = 0; h < 8; h++) {
        #pragma unroll
        for (int n = 0; n < 4; n++) {
            bf16x8 b = *(const bf16x8*)((const short*)W4p
                        + (n * 16 + col) * 256 + h * 32 + quad * 8);
            acc2[n] = __builtin_amdgcn_mfma_f32_16x16x32_bf16(
                          paf[h], b, acc2[n], 0, 0, 0);
        }
    }
    float* obase = out + (size_t)(s * 384 + i0 + wv * 16 + quad * 4) * 64;
    #pragma unroll
    for (int n = 0; n < 4; n++)
        #pragma unroll
        for (int reg = 0; reg < 4; reg++)
            obase[reg * 64 + n * 16 + col] = acc2[n][reg];
}

// ---------------------------------------------------------------------------
extern "C" void kernel_launch(void* const* d_in, const int* in_sizes, int n_in,
                              void* d_out, int out_size, void* d_ws, size_t ws_size,
                              hipStream_t stream)
{
    const float* m_si    = (const float*)d_in[0];
    const float* z_ij    = (const float*)d_in[1];
    const float* gamma_m = (const float*)d_in[2];
    const float* beta_m  = (const float*)d_in[3];
    const float* W1      = (const float*)d_in[4];
    const float* gamma_z = (const float*)d_in[5];
    const float* beta_z  = (const float*)d_in[6];
    const float* W2      = (const float*)d_in[7];
    const float* W3      = (const float*)d_in[8];
    const float* W4      = (const float*)d_in[9];
    float* out = (float*)d_out;

    // ws layout (~209.0 MB):
    //   g_p  : 100663296 B   v_tg : 100663296 B   w_buf(fp32): 4718592 B
    //   w_bf : 2359296 B     W4p  : 32768 B
    //   pm/pl: 294912 B each   Mf/invLf: 12288 B each
    //   W13s : 65536 B, ALIASES w_buf (dead until k2; k1 reads before k2 writes)
    char* ws = (char*)d_ws;
    __hip_bfloat16* g_p  = (__hip_bfloat16*)ws;
    __hip_bfloat16* v_tg = (__hip_bfloat16*)(ws + 100663296);
    float*          w_buf = (float*)(ws + 201326592);
    __hip_bfloat16* W13s = (__hip_bfloat16*)(ws + 201326592);  // alias w_buf
    __hip_bfloat16* w_bf = (__hip_bfloat16*)(ws + 206045184);
    __hip_bfloat16* W4p  = (__hip_bfloat16*)(ws + 208404480);
    float* pm    = (float*)(ws + 208437248);
    float* pl    = (float*)(ws + 208732160);
    float* Mf    = (float*)(ws + 209027072);
    float* invLf = (float*)(ws + 209039360);

    k0_prep  <<<192,  256, 0, stream>>>(W4, W1, W3, W4p, W13s);
    k1_ln_mv <<<1536, 256, 0, stream>>>(m_si, gamma_m, beta_m, W13s, v_tg, g_p);
    k2_ln_z  <<<2304, 256, 0, stream>>>(z_ij, gamma_z, beta_z, W2, w_buf);
    k3a_part <<<192,  128, 0, stream>>>(w_buf, pm, pl);
    k3m_comb <<<8,    384, 0, stream>>>(pm, pl, Mf, invLf);
    k3b_write<<<192,  128, 0, stream>>>(w_buf, Mf, invLf, w_bf);
    k4_mfma  <<<3072, 256, 0, stream>>>(w_bf, v_tg, g_p, W4p, out);
}